// Round 4
// baseline (28081.924 us; speedup 1.0000x reference)
//
#include <hip/hip_runtime.h>
#include <hip/hip_bf16.h>
#include <math.h>

#define BATCH 128
#define LEN   64000
#define FS    256
#define STEPS 200
#define NFILT 64
#define HID   512
#define HID2  512
#define NOUT  10
#define NF    320        // timesteps
#define G4    2048       // 4*HID2
#define KTOT  1024
#define KH    512        // K half per wave
#define NBLK  256        // persistent grid

typedef __bf16  bf16x8 __attribute__((ext_vector_type(8)));
typedef float   f32x4  __attribute__((ext_vector_type(4)));
typedef __hip_bfloat16 hbf;

// ---------------------------------------------------------------------------
// Fast transcendentals
// ---------------------------------------------------------------------------
__device__ __forceinline__ float fsig(float x) {
    return 1.f / (1.f + __expf(-x));
}
__device__ __forceinline__ float ftanh(float x) {
    return 1.f - 2.f / (__expf(2.f * x) + 1.f);
}
__device__ __forceinline__ void imulf_(float al, float au, float bl, float bu,
                                       float& lo, float& hi) {
    const float p1 = al * bl, p2 = al * bu, p3 = au * bl, p4 = au * bu;
    lo = fminf(fminf(p1, p2), fminf(p3, p4));
    hi = fmaxf(fmaxf(p1, p2), fmaxf(p3, p4));
}

// ---------------------------------------------------------------------------
// Frontend: 8 (b,f)-rows per block, one wave per row. Writes bf16 c/r
// with layout [t][b][512].
// ---------------------------------------------------------------------------
__global__ __launch_bounds__(512) void frontend_kernel(
    const float* __restrict__ lb, const float* __restrict__ ub,
    const float* __restrict__ mtx1, const float* __restrict__ mtx2,
    const float* __restrict__ lin1_w, const float* __restrict__ lin1_b,
    hbf* __restrict__ Xc, hbf* __restrict__ Xr)
{
    const int tid  = threadIdx.x;
    const int r    = tid >> 6;
    const int lane = tid & 63;
    const int rowid = blockIdx.x * 8 + r;
    const int f = rowid % NF;
    const int b = rowid / NF;

    __shared__ float sc[8][FS], sr[8][FS];
    __shared__ float s2c[8][FS + 2], s2r[8][FS + 2];
    __shared__ float s3c[8][NFILT], s3r[8][NFILT];

    for (int i = lane; i < FS; i += 64) {
        const int pos = f * STEPS + i;
        float l = 0.f, u = 0.f;
        if (pos < LEN) {
            l = lb[(size_t)b * LEN + pos];
            u = ub[(size_t)b * LEN + pos];
        }
        sc[r][i] = 0.5f * (l + u);
        sr[r][i] = 0.5f * (u - l);
    }
    __syncthreads();

    for (int j = lane; j < FS + 2; j += 64) {
        float oc = 0.f, orr = 0.f;
#pragma unroll 4
        for (int i = 0; i < FS; ++i) {
            const float w = mtx1[i * (FS + 2) + j];
            oc  = fmaf(sc[r][i], w, oc);
            orr = fmaf(sr[r][i], fabsf(w), orr);
        }
        const float l1l = oc - orr, l1u = oc + orr;
        const float a = l1l * l1l, bb = l1u * l1u;
        const float squ = fmaxf(a, bb);
        const float sql = (l1l <= 0.f && l1u >= 0.f) ? 0.f : fminf(a, bb);
        s2c[r][j] = 0.5f * (sql + squ);
        s2r[r][j] = 0.5f * (squ - sql);
    }
    __syncthreads();

    {
        const int j = lane;
        float oc = 1e-10f, orr = 0.f;
#pragma unroll 4
        for (int i = 0; i < FS + 2; ++i) {
            const float w = mtx2[i * NFILT + j];
            oc  = fmaf(s2c[r][i], w, oc);
            orr = fmaf(s2r[r][i], fabsf(w), orr);
        }
        const float lgl = logf(oc - orr);
        const float lgu = logf(oc + orr);
        s3c[r][j] = 0.5f * (lgl + lgu);
        s3r[r][j] = 0.5f * (lgu - lgl);
    }
    __syncthreads();

    for (int j = lane; j < HID; j += 64) {
        float oc = lin1_b[j], orr = 0.f;
#pragma unroll 4
        for (int i = 0; i < NFILT; ++i) {
            const float w = lin1_w[i * HID + j];
            oc  = fmaf(s3c[r][i], w, oc);
            orr = fmaf(s3r[r][i], fabsf(w), orr);
        }
        const float n1l = oc - orr, n1u = oc + orr;
        const float rl = fmaxf(n1l, 0.f), ru = fmaxf(n1u, 0.f);
        const size_t o = ((size_t)f * BATCH + b) * HID + j;
        Xc[o] = __float2bfloat16(0.5f * (rl + ru));
        Xr[o] = __float2bfloat16(0.5f * (ru - rl));
    }
}

// ---------------------------------------------------------------------------
// Weight prep: Wt[n=2048][k=1024] bf16 and |Wt|; k<512 from w_ih, else w_hh.
// ---------------------------------------------------------------------------
__global__ __launch_bounds__(256) void prep_weights_kernel(
    const float* __restrict__ wih, const float* __restrict__ whh,
    hbf* __restrict__ Wt, hbf* __restrict__ Wta)
{
    __shared__ float tile[32][33];
    const int n0 = blockIdx.x * 32;
    const int k0 = blockIdx.y * 32;
    const int tx = threadIdx.x & 31;
    const int ty = threadIdx.x >> 5;

    for (int r = ty; r < 32; r += 8) {
        const int k = k0 + r;
        const float* src = (k < HID) ? (wih + (size_t)k * G4)
                                     : (whh + (size_t)(k - HID) * G4);
        tile[r][tx] = src[n0 + tx];
    }
    __syncthreads();
    for (int r = ty; r < 32; r += 8) {
        const int n = n0 + r;
        const float w = tile[tx][r];
        const size_t o = (size_t)n * KTOT + k0 + tx;
        Wt[o]  = __float2bfloat16(w);
        Wta[o] = __float2bfloat16(fabsf(w));
    }
}

// ---------------------------------------------------------------------------
// Grid-wide barrier: 8 leaf counters (bar[0..7]) + root (bar[8]) + gen (bar[9]).
// 256 blocks, 32 per leaf. Agent-scope atomics, generation-based release.
// ---------------------------------------------------------------------------
__device__ __forceinline__ void grid_barrier(unsigned* bar, int bid, int tid) {
    __syncthreads();
    if (tid == 0) {
        __threadfence();   // prior global writes visible device-wide
        const unsigned g = __hip_atomic_load(&bar[9], __ATOMIC_RELAXED,
                                             __HIP_MEMORY_SCOPE_AGENT);
        const unsigned a = __hip_atomic_fetch_add(&bar[bid & 7], 1u,
                                                  __ATOMIC_ACQ_REL,
                                                  __HIP_MEMORY_SCOPE_AGENT);
        bool released = false;
        if (a == 31u) {
            const unsigned r = __hip_atomic_fetch_add(&bar[8], 1u,
                                                      __ATOMIC_ACQ_REL,
                                                      __HIP_MEMORY_SCOPE_AGENT);
            if (r == 7u) {
                // last block: reset counters, then bump generation (release)
                for (int i = 0; i < 9; ++i)
                    __hip_atomic_store(&bar[i], 0u, __ATOMIC_RELAXED,
                                       __HIP_MEMORY_SCOPE_AGENT);
                __hip_atomic_fetch_add(&bar[9], 1u, __ATOMIC_RELEASE,
                                       __HIP_MEMORY_SCOPE_AGENT);
                released = true;
            }
        }
        if (!released) {
            while (__hip_atomic_load(&bar[9], __ATOMIC_ACQUIRE,
                                     __HIP_MEMORY_SCOPE_AGENT) == g)
                __builtin_amdgcn_s_sleep(2);
        }
    }
    __syncthreads();
}

// ---------------------------------------------------------------------------
// One GEMM phase for one wave: K-half dual-gate MFMA into red[w].
// ---------------------------------------------------------------------------
__device__ __forceinline__ void gemm_phase(
    const hbf* __restrict__ aptr,            // this lane's A row ptr (k-offset in)
    const hbf* const wp[4],                  // this wave's 4 weight-row ptrs
    int lane, float red[4][64][4])
{
    f32x4 a0{0,0,0,0}, a1{0,0,0,0}, a2{0,0,0,0}, a3{0,0,0,0};
#pragma unroll 4
    for (int kk = 0; kk < KH; kk += 32) {
        const bf16x8 av = *(const bf16x8*)(aptr + kk);
        a0 = __builtin_amdgcn_mfma_f32_16x16x32_bf16(av, *(const bf16x8*)(wp[0] + kk), a0, 0, 0, 0);
        a1 = __builtin_amdgcn_mfma_f32_16x16x32_bf16(av, *(const bf16x8*)(wp[1] + kk), a1, 0, 0, 0);
        a2 = __builtin_amdgcn_mfma_f32_16x16x32_bf16(av, *(const bf16x8*)(wp[2] + kk), a2, 0, 0, 0);
        a3 = __builtin_amdgcn_mfma_f32_16x16x32_bf16(av, *(const bf16x8*)(wp[3] + kk), a3, 0, 0, 0);
    }
    *((f32x4*)&red[0][lane][0]) = a0;
    *((f32x4*)&red[1][lane][0]) = a1;
    *((f32x4*)&red[2][lane][0]) = a2;
    *((f32x4*)&red[3][lane][0]) = a3;
}

// ---------------------------------------------------------------------------
// Cell phase: one thread per (m, j) of the 16x16 tile.
// ---------------------------------------------------------------------------
__device__ __forceinline__ void cell_phase(
    float red[4][4][64][4], const float* __restrict__ bias,
    int j0, int m0, int tid,
    float* __restrict__ cl, float* __restrict__ cu,
    hbf* __restrict__ Hco, hbf* __restrict__ Hro,
    float* __restrict__ hl, float* __restrict__ hu, bool writeF)
{
    const int m  = tid >> 4;
    const int j  = tid & 15;
    const int ll = ((m >> 2) << 4) | j;
    const int rr = m & 3;

    float gl[4], gu[4];
#pragma unroll
    for (int g = 0; g < 4; ++g) {
        const float C = red[0][g][ll][rr] + red[2][g][ll][rr];
        const float R = red[1][g][ll][rr] + red[3][g][ll][rr];
        const float bs = bias[g * HID2 + j0 + j];
        gl[g] = C - R + bs;
        gu[g] = C + R + bs;
    }

    const float il = fsig(gl[0]), iu = fsig(gu[0]);
    const float fl = fsig(gl[1]), fu = fsig(gu[1]);
    const float ggl = ftanh(gl[2]), ggu = ftanh(gu[2]);
    const float ol = fsig(gl[3]), ou = fsig(gu[3]);

    const int idx = (m0 + m) * HID2 + j0 + j;
    const float cl0 = cl[idx], cu0 = cu[idx];
    float fcl, fcu, igl, igu;
    imulf_(fl, fu, cl0, cu0, fcl, fcu);
    imulf_(il, iu, ggl, ggu, igl, igu);
    const float ncl = fcl + igl, ncu = fcu + igu;
    cl[idx] = ncl; cu[idx] = ncu;

    float nhl, nhu;
    imulf_(ol, ou, ftanh(ncl), ftanh(ncu), nhl, nhu);
    Hco[idx] = __float2bfloat16(0.5f * (nhl + nhu));
    Hro[idx] = __float2bfloat16(0.5f * (nhu - nhl));
    if (writeF) {
        hl[idx] = nhl;
        hu[idx] = nhu;
    }
}

// ---------------------------------------------------------------------------
// Persistent LSTM: 256 blocks run all 320 steps; 2 phases + 2 barriers/step.
// XCD-aware mapping: xcd = bid&7 owns j-slices [xcd*4, xcd*4+3] x all m-tiles
// so each XCD's ~2MB weight working set stays L2-resident across steps.
// ---------------------------------------------------------------------------
__global__ __launch_bounds__(256) void lstm_persistent(
    const hbf* __restrict__ Xc, const hbf* __restrict__ Xr,
    const hbf* __restrict__ Wt0, const hbf* __restrict__ Wt0a,
    const hbf* __restrict__ Wt1, const hbf* __restrict__ Wt1a,
    const float* __restrict__ b0, const float* __restrict__ b1,
    hbf* __restrict__ H0c0, hbf* __restrict__ H0r0,
    hbf* __restrict__ H0c1, hbf* __restrict__ H0r1,
    hbf* __restrict__ H1c0, hbf* __restrict__ H1r0,
    hbf* __restrict__ H1c1, hbf* __restrict__ H1r1,
    float* __restrict__ c0l, float* __restrict__ c0u,
    float* __restrict__ c1l, float* __restrict__ c1u,
    float* __restrict__ h1l, float* __restrict__ h1u,
    unsigned* __restrict__ bar)
{
    const int tid  = threadIdx.x;
    const int bid  = blockIdx.x;
    const int xcd  = bid & 7;
    const int q    = bid >> 3;            // 0..31
    const int J    = xcd * 4 + (q & 3);   // j-slice 0..31
    const int j0   = J * 16;
    const int m0   = (q >> 2) * 16;       // 0..7 -> m0

    const int w    = tid >> 6;
    const int lane = tid & 63;
    const int op   = w & 1;               // 0 center, 1 radius
    const int ks   = w >> 1;              // K half
    const int rc   = lane & 15;
    const int gk   = lane >> 4;

    __shared__ float red[4][4][64][4];    // 16 KB

    // weight row pointers (constant across steps)
    const hbf* WbL0 = op ? Wt0a : Wt0;
    const hbf* WbL1 = op ? Wt1a : Wt1;
    const hbf* wp0[4];
    const hbf* wp1[4];
#pragma unroll
    for (int g = 0; g < 4; ++g) {
        const size_t row = (size_t)(g * HID2 + j0 + rc) * KTOT + ks * KH + 8 * gk;
        wp0[g] = WbL0 + row;
        wp1[g] = WbL1 + row;
    }

    hbf* H0cb[2] = {H0c0, H0c1};
    hbf* H0rb[2] = {H0r0, H0r1};
    hbf* H1cb[2] = {H1c0, H1c1};
    hbf* H1rb[2] = {H1r0, H1r1};

    const int arow_off = (m0 + rc) * HID + 8 * gk;   // A row offset within a [.][512] buf

    for (int t = 0; t < NF; ++t) {
        const int rd = t & 1, wr2 = rd ^ 1;

        // ---- layer 0: x = X[t], h = H0[rd] ----
        {
            const hbf* Ab;
            if (ks == 0)
                Ab = (op ? Xr : Xc) + (size_t)t * BATCH * HID;
            else
                Ab = op ? H0rb[rd] : H0cb[rd];
            gemm_phase(Ab + arow_off, wp0, lane, red[w]);
        }
        __syncthreads();
        cell_phase(red, b0, j0, m0, tid, c0l, c0u,
                   H0cb[wr2], H0rb[wr2], nullptr, nullptr, false);
        grid_barrier(bar, bid, tid);

        // ---- layer 1: x = H0[wr2], h = H1[rd] ----
        {
            const hbf* Ab;
            if (ks == 0)
                Ab = op ? H0rb[wr2] : H0cb[wr2];
            else
                Ab = op ? H1rb[rd] : H1cb[rd];
            gemm_phase(Ab + arow_off, wp1, lane, red[w]);
        }
        __syncthreads();
        cell_phase(red, b1, j0, m0, tid, c1l, c1u,
                   H1cb[wr2], H1rb[wr2], h1l, h1u, t == NF - 1);
        grid_barrier(bar, bid, tid);
    }
}

// ---------------------------------------------------------------------------
// Final 512 -> 10 interval linear
// ---------------------------------------------------------------------------
__global__ __launch_bounds__(64) void final_kernel(
    const float* __restrict__ h1l, const float* __restrict__ h1u,
    const float* __restrict__ w, const float* __restrict__ bias,
    float* __restrict__ out)
{
    const int b = blockIdx.x;
    const int j = threadIdx.x;
    if (j < NOUT) {
        float oc = bias[j], orr = 0.f;
        for (int i = 0; i < HID2; ++i) {
            const float lo = h1l[(size_t)b * HID2 + i];
            const float hi = h1u[(size_t)b * HID2 + i];
            const float wv = w[i * NOUT + j];
            oc  = fmaf(0.5f * (lo + hi), wv, oc);
            orr = fmaf(0.5f * (hi - lo), fabsf(wv), orr);
        }
        out[b * NOUT + j] = oc - orr;
        out[BATCH * NOUT + b * NOUT + j] = oc + orr;
    }
}

// ---------------------------------------------------------------------------
extern "C" void kernel_launch(void* const* d_in, const int* in_sizes, int n_in,
                              void* d_out, int out_size, void* d_ws, size_t ws_size,
                              hipStream_t stream)
{
    const float* input_lb = (const float*)d_in[0];
    const float* input_ub = (const float*)d_in[1];
    const float* mtx1     = (const float*)d_in[2];
    const float* mtx2     = (const float*)d_in[3];
    const float* lin1_w   = (const float*)d_in[4];
    const float* lin1_b   = (const float*)d_in[5];
    const float* w_ih0    = (const float*)d_in[6];
    const float* w_hh0    = (const float*)d_in[7];
    const float* b0       = (const float*)d_in[8];
    const float* w_ih1    = (const float*)d_in[9];
    const float* w_hh1    = (const float*)d_in[10];
    const float* b1       = (const float*)d_in[11];
    const float* lin2_w   = (const float*)d_in[12];
    const float* lin2_b   = (const float*)d_in[13];
    float* out = (float*)d_out;

    char* ws = (char*)d_ws;
    size_t off = 0;
    hbf* Xc = (hbf*)(ws + off); off += (size_t)NF * BATCH * HID * 2;
    hbf* Xr = (hbf*)(ws + off); off += (size_t)NF * BATCH * HID * 2;
    hbf* Wt0  = (hbf*)(ws + off); off += (size_t)G4 * KTOT * 2;
    hbf* Wt0a = (hbf*)(ws + off); off += (size_t)G4 * KTOT * 2;
    hbf* Wt1  = (hbf*)(ws + off); off += (size_t)G4 * KTOT * 2;
    hbf* Wt1a = (hbf*)(ws + off); off += (size_t)G4 * KTOT * 2;

    // zeroed region: H ping-pong (bf16) + c state (fp32) + barrier
    char* zero_base = ws + off;
    const size_t HSZ = (size_t)BATCH * HID2;
    hbf* H0c[2]; hbf* H0r[2]; hbf* H1c[2]; hbf* H1r[2];
    for (int i = 0; i < 2; ++i) {
        H0c[i] = (hbf*)(ws + off); off += HSZ * 2;
        H0r[i] = (hbf*)(ws + off); off += HSZ * 2;
        H1c[i] = (hbf*)(ws + off); off += HSZ * 2;
        H1r[i] = (hbf*)(ws + off); off += HSZ * 2;
    }
    float* c0l = (float*)(ws + off); off += HSZ * 4;
    float* c0u = (float*)(ws + off); off += HSZ * 4;
    float* c1l = (float*)(ws + off); off += HSZ * 4;
    float* c1u = (float*)(ws + off); off += HSZ * 4;
    unsigned* bar = (unsigned*)(ws + off); off += 64;
    const size_t zero_bytes = (size_t)((ws + off) - zero_base);
    float* h1l = (float*)(ws + off); off += HSZ * 4;
    float* h1u = (float*)(ws + off); off += HSZ * 4;

    hipMemsetAsync(zero_base, 0, zero_bytes, stream);

    {
        const dim3 pgrid(G4 / 32, KTOT / 32);
        prep_weights_kernel<<<pgrid, 256, 0, stream>>>(w_ih0, w_hh0, Wt0, Wt0a);
        prep_weights_kernel<<<pgrid, 256, 0, stream>>>(w_ih1, w_hh1, Wt1, Wt1a);
    }

    frontend_kernel<<<(BATCH * NF) / 8, 512, 0, stream>>>(
        input_lb, input_ub, mtx1, mtx2, lin1_w, lin1_b, Xc, Xr);

    lstm_persistent<<<NBLK, 256, 0, stream>>>(
        Xc, Xr, Wt0, Wt0a, Wt1, Wt1a, b0, b1,
        H0c[0], H0r[0], H0c[1], H0r[1],
        H1c[0], H1r[0], H1c[1], H1r[1],
        c0l, c0u, c1l, c1u, h1l, h1u, bar);

    final_kernel<<<BATCH, 64, 0, stream>>>(h1l, h1u, lin2_w, lin2_b, out);
}

// Round 5
// 15437.903 us; speedup vs baseline: 1.8190x; 1.8190x over previous
//
#include <hip/hip_runtime.h>
#include <hip/hip_bf16.h>
#include <math.h>

#define BATCH 128
#define LEN   64000
#define FS    256
#define STEPS 200
#define NFILT 64
#define HID   512
#define HID2  512
#define NOUT  10
#define NF    320        // timesteps
#define G4    2048       // 4*HID2
#define KTOT  1024
#define KH    512        // K half per wave
#define NBLK  256        // persistent grid

typedef __bf16  bf16x8 __attribute__((ext_vector_type(8)));
typedef float   f32x4  __attribute__((ext_vector_type(4)));
typedef __hip_bfloat16 hbf;

// ---------------------------------------------------------------------------
// Fast transcendentals
// ---------------------------------------------------------------------------
__device__ __forceinline__ float fsig(float x) {
    return 1.f / (1.f + __expf(-x));
}
__device__ __forceinline__ float ftanh(float x) {
    return 1.f - 2.f / (__expf(2.f * x) + 1.f);
}
__device__ __forceinline__ void imulf_(float al, float au, float bl, float bu,
                                       float& lo, float& hi) {
    const float p1 = al * bl, p2 = al * bu, p3 = au * bl, p4 = au * bu;
    lo = fminf(fminf(p1, p2), fminf(p3, p4));
    hi = fmaxf(fmaxf(p1, p2), fmaxf(p3, p4));
}

// ---------------------------------------------------------------------------
// Device-coherent H access (bypasses the non-coherent per-XCD L2 via sc bits,
// no cache-flushing fences). Weights/X stay plain-cached.
// ---------------------------------------------------------------------------
__device__ __forceinline__ bf16x8 loadA16(const hbf* p, bool coh) {
    if (coh) {
        union { unsigned long long u[2]; bf16x8 v; } t;
        unsigned long long* q = (unsigned long long*)p;
        t.u[0] = __hip_atomic_load(q,     __ATOMIC_RELAXED, __HIP_MEMORY_SCOPE_AGENT);
        t.u[1] = __hip_atomic_load(q + 1, __ATOMIC_RELAXED, __HIP_MEMORY_SCOPE_AGENT);
        return t.v;
    }
    return *(const bf16x8*)p;
}
__device__ __forceinline__ void storeH(hbf* p, float v) {
    const __hip_bfloat16 h = __float2bfloat16(v);
    __hip_atomic_store((unsigned short*)p, *(const unsigned short*)&h,
                       __ATOMIC_RELAXED, __HIP_MEMORY_SCOPE_AGENT);
}

// ---------------------------------------------------------------------------
// Frontend: 8 (b,f)-rows per block, one wave per row. Writes bf16 c/r
// with layout [t][b][512].
// ---------------------------------------------------------------------------
__global__ __launch_bounds__(512) void frontend_kernel(
    const float* __restrict__ lb, const float* __restrict__ ub,
    const float* __restrict__ mtx1, const float* __restrict__ mtx2,
    const float* __restrict__ lin1_w, const float* __restrict__ lin1_b,
    hbf* __restrict__ Xc, hbf* __restrict__ Xr)
{
    const int tid  = threadIdx.x;
    const int r    = tid >> 6;
    const int lane = tid & 63;
    const int rowid = blockIdx.x * 8 + r;
    const int f = rowid % NF;
    const int b = rowid / NF;

    __shared__ float sc[8][FS], sr[8][FS];
    __shared__ float s2c[8][FS + 2], s2r[8][FS + 2];
    __shared__ float s3c[8][NFILT], s3r[8][NFILT];

    for (int i = lane; i < FS; i += 64) {
        const int pos = f * STEPS + i;
        float l = 0.f, u = 0.f;
        if (pos < LEN) {
            l = lb[(size_t)b * LEN + pos];
            u = ub[(size_t)b * LEN + pos];
        }
        sc[r][i] = 0.5f * (l + u);
        sr[r][i] = 0.5f * (u - l);
    }
    __syncthreads();

    for (int j = lane; j < FS + 2; j += 64) {
        float oc = 0.f, orr = 0.f;
#pragma unroll 4
        for (int i = 0; i < FS; ++i) {
            const float w = mtx1[i * (FS + 2) + j];
            oc  = fmaf(sc[r][i], w, oc);
            orr = fmaf(sr[r][i], fabsf(w), orr);
        }
        const float l1l = oc - orr, l1u = oc + orr;
        const float a = l1l * l1l, bb = l1u * l1u;
        const float squ = fmaxf(a, bb);
        const float sql = (l1l <= 0.f && l1u >= 0.f) ? 0.f : fminf(a, bb);
        s2c[r][j] = 0.5f * (sql + squ);
        s2r[r][j] = 0.5f * (squ - sql);
    }
    __syncthreads();

    {
        const int j = lane;
        float oc = 1e-10f, orr = 0.f;
#pragma unroll 4
        for (int i = 0; i < FS + 2; ++i) {
            const float w = mtx2[i * NFILT + j];
            oc  = fmaf(s2c[r][i], w, oc);
            orr = fmaf(s2r[r][i], fabsf(w), orr);
        }
        const float lgl = logf(oc - orr);
        const float lgu = logf(oc + orr);
        s3c[r][j] = 0.5f * (lgl + lgu);
        s3r[r][j] = 0.5f * (lgu - lgl);
    }
    __syncthreads();

    for (int j = lane; j < HID; j += 64) {
        float oc = lin1_b[j], orr = 0.f;
#pragma unroll 4
        for (int i = 0; i < NFILT; ++i) {
            const float w = lin1_w[i * HID + j];
            oc  = fmaf(s3c[r][i], w, oc);
            orr = fmaf(s3r[r][i], fabsf(w), orr);
        }
        const float n1l = oc - orr, n1u = oc + orr;
        const float rl = fmaxf(n1l, 0.f), ru = fmaxf(n1u, 0.f);
        const size_t o = ((size_t)f * BATCH + b) * HID + j;
        Xc[o] = __float2bfloat16(0.5f * (rl + ru));
        Xr[o] = __float2bfloat16(0.5f * (ru - rl));
    }
}

// ---------------------------------------------------------------------------
// Weight prep: Wt[n=2048][k=1024] bf16 and |Wt|; k<512 from w_ih, else w_hh.
// ---------------------------------------------------------------------------
__global__ __launch_bounds__(256) void prep_weights_kernel(
    const float* __restrict__ wih, const float* __restrict__ whh,
    hbf* __restrict__ Wt, hbf* __restrict__ Wta)
{
    __shared__ float tile[32][33];
    const int n0 = blockIdx.x * 32;
    const int k0 = blockIdx.y * 32;
    const int tx = threadIdx.x & 31;
    const int ty = threadIdx.x >> 5;

    for (int r = ty; r < 32; r += 8) {
        const int k = k0 + r;
        const float* src = (k < HID) ? (wih + (size_t)k * G4)
                                     : (whh + (size_t)(k - HID) * G4);
        tile[r][tx] = src[n0 + tx];
    }
    __syncthreads();
    for (int r = ty; r < 32; r += 8) {
        const int n = n0 + r;
        const float w = tile[tx][r];
        const size_t o = (size_t)n * KTOT + k0 + tx;
        Wt[o]  = __float2bfloat16(w);
        Wta[o] = __float2bfloat16(fabsf(w));
    }
}

// ---------------------------------------------------------------------------
// Grid-wide barrier, fence-free: relaxed agent-scope atomics ordered by
// explicit s_waitcnt. Never touches the L2 (weights stay resident).
// bar[0..7]=leaves, bar[8]=root, bar[9]=generation.
// ---------------------------------------------------------------------------
__device__ __forceinline__ void grid_barrier(unsigned* bar, int bid, int tid) {
    __builtin_amdgcn_s_waitcnt(0);   // this wave's coherent H-stores are done
    __syncthreads();                 // all waves in block done (waitcnt at barrier)
    if (tid == 0) {
        const unsigned g = __hip_atomic_load(&bar[9], __ATOMIC_RELAXED,
                                             __HIP_MEMORY_SCOPE_AGENT);
        const unsigned a = __hip_atomic_fetch_add(&bar[bid & 7], 1u,
                                                  __ATOMIC_RELAXED,
                                                  __HIP_MEMORY_SCOPE_AGENT);
        bool released = false;
        if (a == 31u) {
            const unsigned r = __hip_atomic_fetch_add(&bar[8], 1u,
                                                      __ATOMIC_RELAXED,
                                                      __HIP_MEMORY_SCOPE_AGENT);
            if (r == 7u) {
                for (int i = 0; i < 9; ++i)
                    __hip_atomic_store(&bar[i], 0u, __ATOMIC_RELAXED,
                                       __HIP_MEMORY_SCOPE_AGENT);
                __builtin_amdgcn_s_waitcnt(0);   // resets visible before release
                __hip_atomic_fetch_add(&bar[9], 1u, __ATOMIC_RELAXED,
                                       __HIP_MEMORY_SCOPE_AGENT);
                released = true;
            }
        }
        if (!released) {
            while (__hip_atomic_load(&bar[9], __ATOMIC_RELAXED,
                                     __HIP_MEMORY_SCOPE_AGENT) == g)
                __builtin_amdgcn_s_sleep(1);
        }
        asm volatile("" ::: "memory");   // no hoisting across the spin
    }
    __syncthreads();
}

// ---------------------------------------------------------------------------
// One GEMM phase for one wave: K-half dual-gate MFMA into red[w].
// coh: A operand needs device-coherent loads (H produced under the barrier).
// ---------------------------------------------------------------------------
__device__ __forceinline__ void gemm_phase(
    const hbf* __restrict__ aptr, bool coh,
    const hbf* const wp[4], int lane, float red[4][64][4])
{
    f32x4 a0{0,0,0,0}, a1{0,0,0,0}, a2{0,0,0,0}, a3{0,0,0,0};
#pragma unroll 4
    for (int kk = 0; kk < KH; kk += 32) {
        const bf16x8 av = loadA16(aptr + kk, coh);
        a0 = __builtin_amdgcn_mfma_f32_16x16x32_bf16(av, *(const bf16x8*)(wp[0] + kk), a0, 0, 0, 0);
        a1 = __builtin_amdgcn_mfma_f32_16x16x32_bf16(av, *(const bf16x8*)(wp[1] + kk), a1, 0, 0, 0);
        a2 = __builtin_amdgcn_mfma_f32_16x16x32_bf16(av, *(const bf16x8*)(wp[2] + kk), a2, 0, 0, 0);
        a3 = __builtin_amdgcn_mfma_f32_16x16x32_bf16(av, *(const bf16x8*)(wp[3] + kk), a3, 0, 0, 0);
    }
    *((f32x4*)&red[0][lane][0]) = a0;
    *((f32x4*)&red[1][lane][0]) = a1;
    *((f32x4*)&red[2][lane][0]) = a2;
    *((f32x4*)&red[3][lane][0]) = a3;
}

// ---------------------------------------------------------------------------
// Cell phase: one thread per (m, j) of the 16x16 tile. H out via coherent
// stores; c state is block-local (plain cached).
// ---------------------------------------------------------------------------
__device__ __forceinline__ void cell_phase(
    float red[4][4][64][4], const float* __restrict__ bias,
    int j0, int m0, int tid,
    float* __restrict__ cl, float* __restrict__ cu,
    hbf* __restrict__ Hco, hbf* __restrict__ Hro,
    float* __restrict__ hl, float* __restrict__ hu, bool writeF)
{
    const int m  = tid >> 4;
    const int j  = tid & 15;
    const int ll = ((m >> 2) << 4) | j;
    const int rr = m & 3;

    float gl[4], gu[4];
#pragma unroll
    for (int g = 0; g < 4; ++g) {
        const float C = red[0][g][ll][rr] + red[2][g][ll][rr];
        const float R = red[1][g][ll][rr] + red[3][g][ll][rr];
        const float bs = bias[g * HID2 + j0 + j];
        gl[g] = C - R + bs;
        gu[g] = C + R + bs;
    }

    const float il = fsig(gl[0]), iu = fsig(gu[0]);
    const float fl = fsig(gl[1]), fu = fsig(gu[1]);
    const float ggl = ftanh(gl[2]), ggu = ftanh(gu[2]);
    const float ol = fsig(gl[3]), ou = fsig(gu[3]);

    const int idx = (m0 + m) * HID2 + j0 + j;
    const float cl0 = cl[idx], cu0 = cu[idx];
    float fcl, fcu, igl, igu;
    imulf_(fl, fu, cl0, cu0, fcl, fcu);
    imulf_(il, iu, ggl, ggu, igl, igu);
    const float ncl = fcl + igl, ncu = fcu + igu;
    cl[idx] = ncl; cu[idx] = ncu;

    float nhl, nhu;
    imulf_(ol, ou, ftanh(ncl), ftanh(ncu), nhl, nhu);
    storeH(&Hco[idx], 0.5f * (nhl + nhu));
    storeH(&Hro[idx], 0.5f * (nhu - nhl));
    if (writeF) {
        hl[idx] = nhl;
        hu[idx] = nhu;
    }
}

// ---------------------------------------------------------------------------
// Persistent LSTM: 256 blocks run all 320 steps; 2 phases + 2 barriers/step.
// XCD-aware mapping keeps each XCD's ~2MB weight slice L2-resident (no
// fences ever invalidate it).
// ---------------------------------------------------------------------------
__global__ __launch_bounds__(256) void lstm_persistent(
    const hbf* __restrict__ Xc, const hbf* __restrict__ Xr,
    const hbf* __restrict__ Wt0, const hbf* __restrict__ Wt0a,
    const hbf* __restrict__ Wt1, const hbf* __restrict__ Wt1a,
    const float* __restrict__ b0, const float* __restrict__ b1,
    hbf* __restrict__ H0c0, hbf* __restrict__ H0r0,
    hbf* __restrict__ H0c1, hbf* __restrict__ H0r1,
    hbf* __restrict__ H1c0, hbf* __restrict__ H1r0,
    hbf* __restrict__ H1c1, hbf* __restrict__ H1r1,
    float* __restrict__ c0l, float* __restrict__ c0u,
    float* __restrict__ c1l, float* __restrict__ c1u,
    float* __restrict__ h1l, float* __restrict__ h1u,
    unsigned* __restrict__ bar)
{
    const int tid  = threadIdx.x;
    const int bid  = blockIdx.x;
    const int xcd  = bid & 7;
    const int q    = bid >> 3;            // 0..31
    const int J    = xcd * 4 + (q & 3);   // j-slice 0..31
    const int j0   = J * 16;
    const int m0   = (q >> 2) * 16;       // 0..7 -> m0

    const int w    = tid >> 6;
    const int lane = tid & 63;
    const int op   = w & 1;               // 0 center, 1 radius
    const int ks   = w >> 1;              // K half
    const int rc   = lane & 15;
    const int gk   = lane >> 4;

    __shared__ float red[4][4][64][4];    // 16 KB

    const hbf* WbL0 = op ? Wt0a : Wt0;
    const hbf* WbL1 = op ? Wt1a : Wt1;
    const hbf* wp0[4];
    const hbf* wp1[4];
#pragma unroll
    for (int g = 0; g < 4; ++g) {
        const size_t row = (size_t)(g * HID2 + j0 + rc) * KTOT + ks * KH + 8 * gk;
        wp0[g] = WbL0 + row;
        wp1[g] = WbL1 + row;
    }

    hbf* H0cb[2] = {H0c0, H0c1};
    hbf* H0rb[2] = {H0r0, H0r1};
    hbf* H1cb[2] = {H1c0, H1c1};
    hbf* H1rb[2] = {H1r0, H1r1};

    const int arow_off = (m0 + rc) * HID + 8 * gk;

    for (int t = 0; t < NF; ++t) {
        const int rd = t & 1, wr2 = rd ^ 1;

        // ---- layer 0: x = X[t] (plain cached), h = H0[rd] (coherent) ----
        {
            const hbf* Ab;
            bool coh;
            if (ks == 0) {
                Ab = (op ? Xr : Xc) + (size_t)t * BATCH * HID;
                coh = false;
            } else {
                Ab = op ? H0rb[rd] : H0cb[rd];
                coh = true;
            }
            gemm_phase(Ab + arow_off, coh, wp0, lane, red[w]);
        }
        __syncthreads();
        cell_phase(red, b0, j0, m0, tid, c0l, c0u,
                   H0cb[wr2], H0rb[wr2], nullptr, nullptr, false);
        grid_barrier(bar, bid, tid);

        // ---- layer 1: x = H0[wr2], h = H1[rd] (both coherent) ----
        {
            const hbf* Ab;
            if (ks == 0)
                Ab = op ? H0rb[wr2] : H0cb[wr2];
            else
                Ab = op ? H1rb[rd] : H1cb[rd];
            gemm_phase(Ab + arow_off, true, wp1, lane, red[w]);
        }
        __syncthreads();
        cell_phase(red, b1, j0, m0, tid, c1l, c1u,
                   H1cb[wr2], H1rb[wr2], h1l, h1u, t == NF - 1);
        grid_barrier(bar, bid, tid);
    }
}

// ---------------------------------------------------------------------------
// Final 512 -> 10 interval linear
// ---------------------------------------------------------------------------
__global__ __launch_bounds__(64) void final_kernel(
    const float* __restrict__ h1l, const float* __restrict__ h1u,
    const float* __restrict__ w, const float* __restrict__ bias,
    float* __restrict__ out)
{
    const int b = blockIdx.x;
    const int j = threadIdx.x;
    if (j < NOUT) {
        float oc = bias[j], orr = 0.f;
        for (int i = 0; i < HID2; ++i) {
            const float lo = h1l[(size_t)b * HID2 + i];
            const float hi = h1u[(size_t)b * HID2 + i];
            const float wv = w[i * NOUT + j];
            oc  = fmaf(0.5f * (lo + hi), wv, oc);
            orr = fmaf(0.5f * (hi - lo), fabsf(wv), orr);
        }
        out[b * NOUT + j] = oc - orr;
        out[BATCH * NOUT + b * NOUT + j] = oc + orr;
    }
}

// ---------------------------------------------------------------------------
extern "C" void kernel_launch(void* const* d_in, const int* in_sizes, int n_in,
                              void* d_out, int out_size, void* d_ws, size_t ws_size,
                              hipStream_t stream)
{
    const float* input_lb = (const float*)d_in[0];
    const float* input_ub = (const float*)d_in[1];
    const float* mtx1     = (const float*)d_in[2];
    const float* mtx2     = (const float*)d_in[3];
    const float* lin1_w   = (const float*)d_in[4];
    const float* lin1_b   = (const float*)d_in[5];
    const float* w_ih0    = (const float*)d_in[6];
    const float* w_hh0    = (const float*)d_in[7];
    const float* b0       = (const float*)d_in[8];
    const float* w_ih1    = (const float*)d_in[9];
    const float* w_hh1    = (const float*)d_in[10];
    const float* b1       = (const float*)d_in[11];
    const float* lin2_w   = (const float*)d_in[12];
    const float* lin2_b   = (const float*)d_in[13];
    float* out = (float*)d_out;

    char* ws = (char*)d_ws;
    size_t off = 0;
    hbf* Xc = (hbf*)(ws + off); off += (size_t)NF * BATCH * HID * 2;
    hbf* Xr = (hbf*)(ws + off); off += (size_t)NF * BATCH * HID * 2;
    hbf* Wt0  = (hbf*)(ws + off); off += (size_t)G4 * KTOT * 2;
    hbf* Wt0a = (hbf*)(ws + off); off += (size_t)G4 * KTOT * 2;
    hbf* Wt1  = (hbf*)(ws + off); off += (size_t)G4 * KTOT * 2;
    hbf* Wt1a = (hbf*)(ws + off); off += (size_t)G4 * KTOT * 2;

    // zeroed region: H ping-pong (bf16) + c state (fp32) + barrier
    char* zero_base = ws + off;
    const size_t HSZ = (size_t)BATCH * HID2;
    hbf* H0c[2]; hbf* H0r[2]; hbf* H1c[2]; hbf* H1r[2];
    for (int i = 0; i < 2; ++i) {
        H0c[i] = (hbf*)(ws + off); off += HSZ * 2;
        H0r[i] = (hbf*)(ws + off); off += HSZ * 2;
        H1c[i] = (hbf*)(ws + off); off += HSZ * 2;
        H1r[i] = (hbf*)(ws + off); off += HSZ * 2;
    }
    float* c0l = (float*)(ws + off); off += HSZ * 4;
    float* c0u = (float*)(ws + off); off += HSZ * 4;
    float* c1l = (float*)(ws + off); off += HSZ * 4;
    float* c1u = (float*)(ws + off); off += HSZ * 4;
    unsigned* bar = (unsigned*)(ws + off); off += 64;
    const size_t zero_bytes = (size_t)((ws + off) - zero_base);
    float* h1l = (float*)(ws + off); off += HSZ * 4;
    float* h1u = (float*)(ws + off); off += HSZ * 4;

    hipMemsetAsync(zero_base, 0, zero_bytes, stream);

    {
        const dim3 pgrid(G4 / 32, KTOT / 32);
        prep_weights_kernel<<<pgrid, 256, 0, stream>>>(w_ih0, w_hh0, Wt0, Wt0a);
        prep_weights_kernel<<<pgrid, 256, 0, stream>>>(w_ih1, w_hh1, Wt1, Wt1a);
    }

    frontend_kernel<<<(BATCH * NF) / 8, 512, 0, stream>>>(
        input_lb, input_ub, mtx1, mtx2, lin1_w, lin1_b, Xc, Xr);

    lstm_persistent<<<NBLK, 256, 0, stream>>>(
        Xc, Xr, Wt0, Wt0a, Wt1, Wt1a, b0, b1,
        H0c[0], H0r[0], H0c[1], H0r[1],
        H1c[0], H1r[0], H1c[1], H1r[1],
        c0l, c0u, c1l, c1u, h1l, h1u, bar);

    final_kernel<<<BATCH, 64, 0, stream>>>(h1l, h1u, lin2_w, lin2_b, out);
}